// Round 1
// baseline (14666.397 us; speedup 1.0000x reference)
//
#include <hip/hip_runtime.h>
#include <math.h>

// APDIntelligibilityEstimator — full fp32 implementation (v1: correctness-first).
//
// Key identity: bit_conv1d(x,w,s) == conv(x, sign(w)) * mean|w| * s  (x_scale cancels).
// bit_linear keeps x_scale only on the bias term.
//
// Workspace layout (needs ~209 MB):
//   bufA : (B, 512, TPAD) f32 trunk
//   bufB : (B, 512, TPAD) f32 activation scratch (bn output uses first half)
//   h0   : (B, 512) f32 pooled features
//   stats: 1024 f32  — [slot*32 + b*2] = {sum, sumsq} for 25 GroupNorms;
//                      [800..827] = sum|w| for bn, ti, pw[0..23], fc1, fco

#define EPSF 1e-5f

constexpr int B_   = 16;
constexpr int TIN  = 64000;
constexpr int TOUT = 3201;
constexpr int TPAD = 3328;   // 52*64, 26*128
constexpr int E_   = 512;
constexpr int BNC  = 256;
constexpr int C_   = 512;
constexpr int NT   = 24;
constexpr int H_   = 256;

__device__ __forceinline__ float fsign(float w) {
    return (w > 0.f) ? 1.f : ((w < 0.f) ? -1.f : 0.f);
}

// block of 256 threads (4 waves); returns total on ALL threads
__device__ float blockReduceSumB(float v, float* red) {
    __syncthreads();                       // protect red[] reuse across calls
    int lane = threadIdx.x & 63, wid = threadIdx.x >> 6;
#pragma unroll
    for (int o = 32; o > 0; o >>= 1) v += __shfl_down(v, o, 64);
    if (lane == 0) red[wid] = v;
    __syncthreads();
    if (threadIdx.x == 0) red[0] = red[0] + red[1] + red[2] + red[3];
    __syncthreads();
    return red[0];
}

// --- sum of |w| over a tensor slice (atomic into out[slice]) ---------------
__global__ void k_absmean(const float* __restrict__ p, int n, int slice_stride,
                          float* __restrict__ out) {
    __shared__ float red[4];
    const float* q = p + (size_t)blockIdx.y * (size_t)slice_stride;
    float s = 0.f;
    for (int i = blockIdx.x * blockDim.x + threadIdx.x; i < n;
         i += gridDim.x * blockDim.x)
        s += fabsf(q[i]);
    s = blockReduceSumB(s, red);
    if (threadIdx.x == 0) atomicAdd(out + blockIdx.y, s);
}

// --- encoder conv (k=40, s=20, p=20) + GN partial stats --------------------
__global__ void k_encoder(const float* __restrict__ x, const float* __restrict__ w,
                          float* __restrict__ out, float* __restrict__ stats) {
    __shared__ float wsm[40];
    __shared__ float red[4];
    int e = blockIdx.x, b = blockIdx.y;
    if (threadIdx.x < 40) wsm[threadIdx.x] = w[e * 40 + threadIdx.x];
    __syncthreads();
    const float* xb = x + (size_t)b * TIN;
    float* ob = out + ((size_t)b * E_ + e) * TPAD;
    float ls = 0.f, lq = 0.f;
    for (int t = threadIdx.x; t < TPAD; t += 256) {
        if (t < TOUT) {
            int base = 20 * t - 20;
            float s = 0.f;
            if (base >= 0 && base + 39 < TIN) {
#pragma unroll 8
                for (int k = 0; k < 40; ++k) s += wsm[k] * xb[base + k];
            } else {
                for (int k = 0; k < 40; ++k) {
                    int p = base + k;
                    if (p >= 0 && p < TIN) s += wsm[k] * xb[p];
                }
            }
            ob[t] = s; ls += s; lq += s * s;
        } else {
            ob[t] = 0.f;   // keep pad clean
        }
    }
    ls = blockReduceSumB(ls, red);
    lq = blockReduceSumB(lq, red);
    if (threadIdx.x == 0) {
        atomicAdd(stats + b * 2, ls);
        atomicAdd(stats + b * 2 + 1, lq);
    }
}

// --- GroupNorm(1) apply + PReLU, in place (valid t only; pad untouched) ----
__global__ void k_gn_prelu(float* __restrict__ buf, const float* __restrict__ stats,
                           const float* __restrict__ gamma, const float* __restrict__ beta,
                           const float* __restrict__ prelu, float invN) {
    int c = blockIdx.x, b = blockIdx.y;
    float s0 = stats[b * 2], s1 = stats[b * 2 + 1];
    float mean = s0 * invN;
    float var  = s1 * invN - mean * mean;
    float inv  = rsqrtf(var + EPSF);
    float sc = gamma[c] * inv;
    float sh = beta[c] - mean * sc;
    float a  = prelu[0];
    float* p = buf + ((size_t)b * gridDim.x + c) * TPAD;
    for (int t = threadIdx.x; t < TOUT; t += 256) {
        float v = p[t] * sc + sh;
        p[t] = (v >= 0.f) ? v : a * v;
    }
}

// --- depthwise conv k=3 dilation d + GN partial stats ----------------------
__global__ void k_dwconv(const float* __restrict__ f, const float* __restrict__ w,
                         float* __restrict__ act, float* __restrict__ stats, int d) {
    __shared__ float red[4];
    int c = blockIdx.x, b = blockIdx.y;
    float w0 = w[c * 3], w1 = w[c * 3 + 1], w2 = w[c * 3 + 2];
    const float* src = f + ((size_t)b * C_ + c) * TPAD;
    float* dst = act + ((size_t)b * C_ + c) * TPAD;
    float ls = 0.f, lq = 0.f;
    for (int t = threadIdx.x; t < TPAD; t += 256) {
        if (t < TOUT) {
            float v = w1 * src[t];
            if (t >= d)        v += w0 * src[t - d];
            if (t + d < TOUT)  v += w2 * src[t + d];
            dst[t] = v; ls += v; lq += v * v;
        } else {
            dst[t] = 0.f;
        }
    }
    ls = blockReduceSumB(ls, red);
    lq = blockReduceSumB(lq, red);
    if (threadIdx.x == 0) {
        atomicAdd(stats + b * 2, ls);
        atomicAdd(stats + b * 2 + 1, lq);
    }
}

// --- pointwise GEMM with sign(W):  Y[b,m,t] (+)= alpha * sum_k sign(W[m,k]) X[b,k,t]
// alpha = wsum[0]*inv_nw*scale[0].  64x64 tile, BK=32, 256 threads, 4x4/thread.
__global__ __launch_bounds__(256) void k_gemm_sign(
    const float* __restrict__ W, const float* __restrict__ X, float* __restrict__ Y,
    const float* __restrict__ wsum, float inv_nw, const float* __restrict__ scale,
    int M, int K, int acc_mode) {
    __shared__ __align__(16) float As[32][68];   // [k][m], +4 pad keeps 16B align
    __shared__ __align__(16) float Bs[32][64];   // [k][n]
    int b  = blockIdx.z;
    int n0 = blockIdx.x * 64, m0 = blockIdx.y * 64;
    const float* Xb = X + (size_t)b * K * TPAD;
    float* Yb = Y + (size_t)b * M * TPAD;
    int tid = threadIdx.x;
    int tx = tid & 15, ty = tid >> 4;
    float acc[4][4] = {};
    for (int k0 = 0; k0 < K; k0 += 32) {
#pragma unroll
        for (int j = 0; j < 8; ++j) {            // A tile: 64x32
            int idx = j * 256 + tid;
            int m = idx >> 5, k = idx & 31;
            As[k][m] = fsign(W[(size_t)(m0 + m) * K + k0 + k]);
        }
#pragma unroll
        for (int j = 0; j < 8; ++j) {            // B tile: 32x64
            int idx = j * 256 + tid;
            int k = idx >> 6, n = idx & 63;
            Bs[k][n] = Xb[(size_t)(k0 + k) * TPAD + n0 + n];
        }
        __syncthreads();
#pragma unroll
        for (int kk = 0; kk < 32; ++kk) {
            float4 a4 = *(const float4*)&As[kk][ty * 4];
            float4 b4 = *(const float4*)&Bs[kk][tx * 4];
            float av[4] = {a4.x, a4.y, a4.z, a4.w};
            float bv[4] = {b4.x, b4.y, b4.z, b4.w};
#pragma unroll
            for (int i = 0; i < 4; ++i)
#pragma unroll
                for (int j2 = 0; j2 < 4; ++j2)
                    acc[i][j2] += av[i] * bv[j2];
        }
        __syncthreads();
    }
    float alpha = wsum[0] * inv_nw * scale[0];
#pragma unroll
    for (int i = 0; i < 4; ++i) {
        int row = m0 + ty * 4 + i;
        float4* yp = (float4*)&Yb[(size_t)row * TPAD + n0 + tx * 4];
        float4 v;
        v.x = alpha * acc[i][0]; v.y = alpha * acc[i][1];
        v.z = alpha * acc[i][2]; v.w = alpha * acc[i][3];
        if (acc_mode) {
            float4 o = *yp;
            v.x += o.x; v.y += o.y; v.z += o.z; v.w += o.w;
        }
        *yp = v;
    }
}

// --- temporal mean ---------------------------------------------------------
__global__ void k_tmean(const float* __restrict__ f, float* __restrict__ h0) {
    __shared__ float red[4];
    int c = blockIdx.x, b = blockIdx.y;
    const float* p = f + ((size_t)b * C_ + c) * TPAD;
    float s = 0.f;
    for (int t = threadIdx.x; t < TOUT; t += 256) s += p[t];
    s = blockReduceSumB(s, red);
    if (threadIdx.x == 0) h0[b * C_ + c] = s / (float)TOUT;
}

// --- head: bit_linear -> PReLU -> bit_linear -> sigmoid (one block per b) --
__global__ void k_head(const float* __restrict__ h0,
                       const float* __restrict__ fc1_w, const float* __restrict__ fc1_b,
                       const float* __restrict__ fc1_scale, const float* __restrict__ head_prelu,
                       const float* __restrict__ fco_w, const float* __restrict__ fco_b,
                       const float* __restrict__ fco_scale,
                       const float* __restrict__ wsums, float* __restrict__ out) {
    __shared__ float sh0[512];
    __shared__ float red[4];
    int b = blockIdx.x, tid = threadIdx.x;
    sh0[tid]       = h0[b * C_ + tid];
    sh0[tid + 256] = h0[b * C_ + 256 + tid];
    __syncthreads();
    float av = fabsf(sh0[tid]) + fabsf(sh0[tid + 256]);
    float xs1 = blockReduceSumB(av, red) / 512.f;
    xs1 = fmaxf(xs1, EPSF);
    float ws1 = wsums[26] / 131072.f;      // mean|fc1_w|, 256*512
    float sc1 = fc1_scale[0];
    const float* wrow = fc1_w + tid * 512;
    float s = 0.f;
    for (int c = 0; c < 512; ++c) s += sh0[c] * fsign(wrow[c]);
    float h1 = s * ws1 * sc1 + fc1_b[tid] * ws1 * xs1 * sc1;
    float a = head_prelu[0];
    h1 = (h1 >= 0.f) ? h1 : a * h1;
    float xs2 = blockReduceSumB(fabsf(h1), red) / 256.f;
    xs2 = fmaxf(xs2, EPSF);
    float zpart = h1 * fsign(fco_w[tid]);
    float z = blockReduceSumB(zpart, red);
    if (tid == 0) {
        float ws2 = wsums[27] / 256.f;     // mean|fco_w|
        float sc2 = fco_scale[0];
        z = z * ws2 * sc2 + fco_b[0] * ws2 * xs2 * sc2;
        out[b] = 1.f / (1.f + expf(-z));
    }
}

extern "C" void kernel_launch(void* const* d_in, const int* in_sizes, int n_in,
                              void* d_out, int out_size, void* d_ws, size_t ws_size,
                              hipStream_t stream) {
    const float* x        = (const float*)d_in[0];
    const float* enc_w    = (const float*)d_in[1];
    const float* enc_g    = (const float*)d_in[2];
    const float* enc_be   = (const float*)d_in[3];
    const float* enc_pr   = (const float*)d_in[4];
    const float* bn_w     = (const float*)d_in[5];
    const float* bn_scale = (const float*)d_in[6];
    const float* ti_w     = (const float*)d_in[7];
    const float* ti_scale = (const float*)d_in[8];
    const float* dw_w     = (const float*)d_in[9];
    const float* pw_w     = (const float*)d_in[10];
    const float* pw_scale = (const float*)d_in[11];
    const float* tg       = (const float*)d_in[12];
    const float* tb       = (const float*)d_in[13];
    const float* tp       = (const float*)d_in[14];
    const float* fc1_w    = (const float*)d_in[15];
    const float* fc1_b    = (const float*)d_in[16];
    const float* fc1_s    = (const float*)d_in[17];
    const float* head_pr  = (const float*)d_in[18];
    const float* fco_w    = (const float*)d_in[19];
    const float* fco_b    = (const float*)d_in[20];
    const float* fco_s    = (const float*)d_in[21];
    float* out = (float*)d_out;

    char* ws = (char*)d_ws;
    size_t fmap = (size_t)B_ * C_ * TPAD * sizeof(float);   // 109,051,904 B
    float* bufA  = (float*)ws;
    float* bufB  = (float*)(ws + fmap);
    float* h0    = (float*)(ws + 2 * fmap);
    float* stats = (float*)(ws + 2 * fmap + (size_t)B_ * C_ * sizeof(float));
    float* wsums = stats + 800;

    hipMemsetAsync(stats, 0, 1024 * sizeof(float), stream);

    // weight |.| sums
    k_absmean<<<dim3(8, 1),  256, 0, stream>>>(bn_w,  BNC * C_, 0,        wsums + 0);
    k_absmean<<<dim3(8, 1),  256, 0, stream>>>(ti_w,  C_ * BNC, 0,        wsums + 1);
    k_absmean<<<dim3(8, NT), 256, 0, stream>>>(pw_w,  C_ * C_,  C_ * C_,  wsums + 2);
    k_absmean<<<dim3(8, 1),  256, 0, stream>>>(fc1_w, H_ * C_,  0,        wsums + 26);
    k_absmean<<<dim3(1, 1),  256, 0, stream>>>(fco_w, H_,       0,        wsums + 27);

    // encoder + GN + PReLU
    k_encoder<<<dim3(E_, B_), 256, 0, stream>>>(x, enc_w, bufA, stats);
    k_gn_prelu<<<dim3(E_, B_), 256, 0, stream>>>(bufA, stats, enc_g, enc_be, enc_pr,
                                                 1.f / ((float)E_ * TOUT));
    // bottleneck 512->256, then tcn_input 256->512
    k_gemm_sign<<<dim3(TPAD / 64, BNC / 64, B_), 256, 0, stream>>>(
        bn_w, bufA, bufB, wsums + 0, 1.f / (BNC * C_), bn_scale, BNC, C_, 0);
    k_gemm_sign<<<dim3(TPAD / 64, C_ / 64, B_), 256, 0, stream>>>(
        ti_w, bufB, bufA, wsums + 1, 1.f / (C_ * BNC), ti_scale, C_, BNC, 0);

    // 24 TCN layers
    for (int i = 0; i < NT; ++i) {
        int d = 1 << (i & 7);
        float* st = stats + (1 + i) * 32;
        k_dwconv<<<dim3(C_, B_), 256, 0, stream>>>(bufA, dw_w + (size_t)i * C_ * 3,
                                                   bufB, st, d);
        k_gn_prelu<<<dim3(C_, B_), 256, 0, stream>>>(bufB, st, tg + i * C_, tb + i * C_,
                                                     tp + i, 1.f / ((float)C_ * TOUT));
        k_gemm_sign<<<dim3(TPAD / 64, C_ / 64, B_), 256, 0, stream>>>(
            pw_w + (size_t)i * C_ * C_, bufB, bufA, wsums + 2 + i,
            1.f / (C_ * C_), pw_scale + i, C_, C_, 1);
    }

    // head
    k_tmean<<<dim3(C_, B_), 256, 0, stream>>>(bufA, h0);
    k_head<<<dim3(B_), 256, 0, stream>>>(h0, fc1_w, fc1_b, fc1_s, head_pr,
                                         fco_w, fco_b, fco_s, wsums, out);
}

// Round 2
// 9301.662 us; speedup vs baseline: 1.5768x; 1.5768x over previous
//
#include <hip/hip_runtime.h>
#include <hip/hip_bf16.h>
#include <math.h>

// APDIntelligibilityEstimator v2 — bf16 MFMA for all pointwise (sign-weight) GEMMs.
//
// bit_conv1d(x,w,s) == conv(x, sign(w)) * mean|w| * s  (x_scale cancels).
// Activations for GEMM stored transposed bf16 [t][c] so both MFMA operands
// read contiguous-k 16B fragments from row-major LDS.
//
// Workspace (~218 MB):
//   bufA : (B, 512, TPAD) f32   — residual trunk
//   SCR  : 54.5 MB              — dwconv/encoder out (bf16 [c][t]) OR bn-gemm out (bf16 [m][t])
//   Xb   : (B, TPAD, 512) bf16  — transposed GN'd activations (GEMM B operand)
//   h0, stats/wsums

#define EPSF 1e-5f

constexpr int B_   = 16;
constexpr int TIN  = 64000;
constexpr int TOUT = 3201;
constexpr int TPAD = 3328;   // 26*128
constexpr int E_   = 512;
constexpr int BNC  = 256;
constexpr int C_   = 512;
constexpr int NT   = 24;
constexpr int H_   = 256;

typedef __attribute__((ext_vector_type(8))) short short8;
typedef __attribute__((ext_vector_type(4))) float floatx4;

__device__ __forceinline__ float fsign(float w) {
    return (w > 0.f) ? 1.f : ((w < 0.f) ? -1.f : 0.f);
}
__device__ __forceinline__ short bsign(float w) {
    return (w > 0.f) ? (short)0x3F80 : ((w < 0.f) ? (short)0xBF80 : (short)0);
}

__device__ float blockReduceSumB(float v, float* red) {
    __syncthreads();
    int lane = threadIdx.x & 63, wid = threadIdx.x >> 6;
#pragma unroll
    for (int o = 32; o > 0; o >>= 1) v += __shfl_down(v, o, 64);
    if (lane == 0) red[wid] = v;
    __syncthreads();
    if (threadIdx.x == 0) red[0] = red[0] + red[1] + red[2] + red[3];
    __syncthreads();
    return red[0];
}

// --- sum|w| ----------------------------------------------------------------
__global__ void k_absmean(const float* __restrict__ p, int n, int slice_stride,
                          float* __restrict__ out) {
    __shared__ float red[4];
    const float* q = p + (size_t)blockIdx.y * (size_t)slice_stride;
    float s = 0.f;
    for (int i = blockIdx.x * blockDim.x + threadIdx.x; i < n;
         i += gridDim.x * blockDim.x)
        s += fabsf(q[i]);
    s = blockReduceSumB(s, red);
    if (threadIdx.x == 0) atomicAdd(out + blockIdx.y, s);
}

// --- encoder conv (k=40,s=20,p=20) -> bf16 [e][t] + GN stats ---------------
__global__ void k_encoder(const float* __restrict__ x, const float* __restrict__ w,
                          __hip_bfloat16* __restrict__ out, float* __restrict__ stats) {
    __shared__ float wsm[40];
    __shared__ float red[4];
    int e = blockIdx.x, b = blockIdx.y;
    if (threadIdx.x < 40) wsm[threadIdx.x] = w[e * 40 + threadIdx.x];
    __syncthreads();
    const float* xb = x + (size_t)b * TIN;
    __hip_bfloat16* ob = out + ((size_t)b * E_ + e) * TPAD;
    float ls = 0.f, lq = 0.f;
    for (int t = threadIdx.x; t < TPAD; t += 256) {
        if (t < TOUT) {
            int base = 20 * t - 20;
            float s = 0.f;
            if (base >= 0 && base + 39 < TIN) {
#pragma unroll 8
                for (int k = 0; k < 40; ++k) s += wsm[k] * xb[base + k];
            } else {
                for (int k = 0; k < 40; ++k) {
                    int p = base + k;
                    if (p >= 0 && p < TIN) s += wsm[k] * xb[p];
                }
            }
            ob[t] = __float2bfloat16(s); ls += s; lq += s * s;
        } else {
            ob[t] = __float2bfloat16(0.f);
        }
    }
    ls = blockReduceSumB(ls, red);
    lq = blockReduceSumB(lq, red);
    if (threadIdx.x == 0) {
        atomicAdd(stats + b * 2, ls);
        atomicAdd(stats + b * 2 + 1, lq);
    }
}

// --- depthwise conv k=3 dil d : trunk f32 [c][t] -> bf16 [c][t] + stats ----
__global__ void k_dwconv(const float* __restrict__ f, const float* __restrict__ w,
                         __hip_bfloat16* __restrict__ act, float* __restrict__ stats,
                         int d) {
    __shared__ float red[4];
    int c = blockIdx.x, b = blockIdx.y;
    float w0 = w[c * 3], w1 = w[c * 3 + 1], w2 = w[c * 3 + 2];
    const float* src = f + ((size_t)b * C_ + c) * TPAD;
    __hip_bfloat16* dst = act + ((size_t)b * C_ + c) * TPAD;
    float ls = 0.f, lq = 0.f;
    for (int t = threadIdx.x; t < TPAD; t += 256) {
        if (t < TOUT) {
            float v = w1 * src[t];
            if (t >= d)        v += w0 * src[t - d];
            if (t + d < TOUT)  v += w2 * src[t + d];
            dst[t] = __float2bfloat16(v); ls += v; lq += v * v;
        } else {
            dst[t] = __float2bfloat16(0.f);
        }
    }
    ls = blockReduceSumB(ls, red);
    lq = blockReduceSumB(lq, red);
    if (threadIdx.x == 0) {
        atomicAdd(stats + b * 2, ls);
        atomicAdd(stats + b * 2 + 1, lq);
    }
}

// --- GN+PReLU (optional) + transpose: bf16 [C][TPAD] -> bf16 [TPAD][C] -----
__global__ void k_gncvt(const __hip_bfloat16* __restrict__ in,
                        __hip_bfloat16* __restrict__ outT,
                        const float* __restrict__ stats,
                        const float* __restrict__ gamma, const float* __restrict__ beta,
                        const float* __restrict__ prelu, float invN, int C, int do_gn) {
    __shared__ __hip_bfloat16 tile[64][72];
    int b = blockIdx.z;
    int t0 = blockIdx.x * 64, c0 = blockIdx.y * 64;
    const __hip_bfloat16* ip = in + (size_t)b * C * TPAD;
    __hip_bfloat16* op = outT + (size_t)b * TPAD * C;
    int tid = threadIdx.x;
    float mean = 0.f, inv = 1.f, a = 0.f;
    if (do_gn) {
        float s0 = stats[b * 2], s1 = stats[b * 2 + 1];
        mean = s0 * invN;
        float var = s1 * invN - mean * mean;
        inv = rsqrtf(var + EPSF);
        a = prelu[0];
    }
#pragma unroll
    for (int q = 0; q < 2; ++q) {
        int id = q * 256 + tid;
        int r = id >> 3, cc = id & 7;
        union { short8 v; __hip_bfloat16 h[8]; } u;
        u.v = *(const short8*)(ip + (size_t)(c0 + r) * TPAD + t0 + cc * 8);
        if (do_gn) {
            float sc = gamma[c0 + r] * inv;
            float sh = beta[c0 + r] - mean * sc;
#pragma unroll
            for (int e = 0; e < 8; ++e) {
                float v = __bfloat162float(u.h[e]) * sc + sh;
                v = (v >= 0.f) ? v : a * v;
                u.h[e] = __float2bfloat16(v);
            }
        }
        *(short8*)&tile[r][cc * 8] = u.v;
    }
    __syncthreads();
#pragma unroll
    for (int q = 0; q < 2; ++q) {
        int id = q * 256 + tid;
        int tr = id >> 3, c8 = id & 7;
        union { short8 v; __hip_bfloat16 h[8]; } u;
#pragma unroll
        for (int e = 0; e < 8; ++e) u.h[e] = tile[c8 * 8 + e][tr];
        *(short8*)(op + (size_t)(t0 + tr) * C + c0 + c8 * 8) = u.v;
    }
}

// --- MFMA GEMM: Y[b,m,n] = alpha * sum_k sign(W[m,k]) * X[b,n,k]  ----------
// W: f32 [M][K] raw (sign taken during staging). Xb: bf16 [TPAD][K].
// mode 0: f32 store   1: f32 acc(residual)+store   2: bf16 store
__global__ __launch_bounds__(256) void k_gemm_mfma(
    const float* __restrict__ W, const __hip_bfloat16* __restrict__ Xb,
    float* __restrict__ Yf, __hip_bfloat16* __restrict__ Yh,
    const float* __restrict__ wsum, float inv_nw, const float* __restrict__ scale,
    int M, int K, int mode) {
    __shared__ __align__(16) short As[128 * 64];
    __shared__ __align__(16) short Bs[128 * 64];
    int b = blockIdx.z;
    int n0 = blockIdx.x * 128, m0 = blockIdx.y * 128;
    const __hip_bfloat16* Xp = Xb + (size_t)b * TPAD * K;
    int tid = threadIdx.x;
    int lane = tid & 63, wid = tid >> 6;
    int wr = wid >> 1, wc = wid & 1;
    int l15 = lane & 15, quad = lane >> 4;
    floatx4 acc[4][4];
#pragma unroll
    for (int i = 0; i < 4; ++i)
#pragma unroll
        for (int j = 0; j < 4; ++j) acc[i][j] = (floatx4){0.f, 0.f, 0.f, 0.f};

    for (int k0 = 0; k0 < K; k0 += 64) {
#pragma unroll
        for (int j = 0; j < 4; ++j) {                    // A: 128x64, sign->bf16
            int id = j * 256 + tid;
            int r = id >> 3, c = id & 7;
            const float* wp = W + (size_t)(m0 + r) * K + k0 + c * 8;
            short8 v;
#pragma unroll
            for (int e = 0; e < 8; ++e) v[e] = bsign(wp[e]);
            int sw = c ^ (r & 7);
            *(short8*)&As[r * 64 + sw * 8] = v;
        }
#pragma unroll
        for (int j = 0; j < 4; ++j) {                    // B: 128x64 from [t][k]
            int id = j * 256 + tid;
            int r = id >> 3, c = id & 7;
            short8 v = *(const short8*)(Xp + (size_t)(n0 + r) * K + k0 + c * 8);
            int sw = c ^ (r & 7);
            *(short8*)&Bs[r * 64 + sw * 8] = v;
        }
        __syncthreads();
#pragma unroll
        for (int s = 0; s < 2; ++s) {
            short8 af[4], bf[4];
#pragma unroll
            for (int i = 0; i < 4; ++i) {
                int row = wr * 64 + i * 16 + l15;
                int ch = (s * 4 + quad) ^ (row & 7);
                af[i] = *(const short8*)&As[row * 64 + ch * 8];
            }
#pragma unroll
            for (int j = 0; j < 4; ++j) {
                int row = wc * 64 + j * 16 + l15;
                int ch = (s * 4 + quad) ^ (row & 7);
                bf[j] = *(const short8*)&Bs[row * 64 + ch * 8];
            }
#pragma unroll
            for (int i = 0; i < 4; ++i)
#pragma unroll
                for (int j = 0; j < 4; ++j)
                    acc[i][j] = __builtin_amdgcn_mfma_f32_16x16x32_bf16(
                        af[i], bf[j], acc[i][j], 0, 0, 0);
        }
        __syncthreads();
    }
    float alpha = wsum[0] * inv_nw * scale[0];
#pragma unroll
    for (int i = 0; i < 4; ++i) {
#pragma unroll
        for (int j = 0; j < 4; ++j) {
            int mbase = m0 + wr * 64 + i * 16 + quad * 4;
            int n = n0 + wc * 64 + j * 16 + l15;
#pragma unroll
            for (int r = 0; r < 4; ++r) {
                int m = mbase + r;
                float v = alpha * acc[i][j][r];
                if (mode == 2) {
                    Yh[(size_t)b * M * TPAD + (size_t)m * TPAD + n] = __float2bfloat16(v);
                } else {
                    float* yp = Yf + (size_t)b * M * TPAD + (size_t)m * TPAD + n;
                    if (mode == 1) v += *yp;
                    *yp = v;
                }
            }
        }
    }
}

// --- temporal mean ---------------------------------------------------------
__global__ void k_tmean(const float* __restrict__ f, float* __restrict__ h0) {
    __shared__ float red[4];
    int c = blockIdx.x, b = blockIdx.y;
    const float* p = f + ((size_t)b * C_ + c) * TPAD;
    float s = 0.f;
    for (int t = threadIdx.x; t < TOUT; t += 256) s += p[t];
    s = blockReduceSumB(s, red);
    if (threadIdx.x == 0) h0[b * C_ + c] = s / (float)TOUT;
}

// --- head ------------------------------------------------------------------
__global__ void k_head(const float* __restrict__ h0,
                       const float* __restrict__ fc1_w, const float* __restrict__ fc1_b,
                       const float* __restrict__ fc1_scale, const float* __restrict__ head_prelu,
                       const float* __restrict__ fco_w, const float* __restrict__ fco_b,
                       const float* __restrict__ fco_scale,
                       const float* __restrict__ wsums, float* __restrict__ out) {
    __shared__ float sh0[512];
    __shared__ float red[4];
    int b = blockIdx.x, tid = threadIdx.x;
    sh0[tid]       = h0[b * C_ + tid];
    sh0[tid + 256] = h0[b * C_ + 256 + tid];
    __syncthreads();
    float av = fabsf(sh0[tid]) + fabsf(sh0[tid + 256]);
    float xs1 = blockReduceSumB(av, red) / 512.f;
    xs1 = fmaxf(xs1, EPSF);
    float ws1 = wsums[26] / 131072.f;
    float sc1 = fc1_scale[0];
    const float* wrow = fc1_w + tid * 512;
    float s = 0.f;
    for (int c = 0; c < 512; ++c) s += sh0[c] * fsign(wrow[c]);
    float h1 = s * ws1 * sc1 + fc1_b[tid] * ws1 * xs1 * sc1;
    float a = head_prelu[0];
    h1 = (h1 >= 0.f) ? h1 : a * h1;
    float xs2 = blockReduceSumB(fabsf(h1), red) / 256.f;
    xs2 = fmaxf(xs2, EPSF);
    float zpart = h1 * fsign(fco_w[tid]);
    float z = blockReduceSumB(zpart, red);
    if (tid == 0) {
        float ws2 = wsums[27] / 256.f;
        float sc2 = fco_scale[0];
        z = z * ws2 * sc2 + fco_b[0] * ws2 * xs2 * sc2;
        out[b] = 1.f / (1.f + expf(-z));
    }
}

extern "C" void kernel_launch(void* const* d_in, const int* in_sizes, int n_in,
                              void* d_out, int out_size, void* d_ws, size_t ws_size,
                              hipStream_t stream) {
    const float* x        = (const float*)d_in[0];
    const float* enc_w    = (const float*)d_in[1];
    const float* enc_g    = (const float*)d_in[2];
    const float* enc_be   = (const float*)d_in[3];
    const float* enc_pr   = (const float*)d_in[4];
    const float* bn_w     = (const float*)d_in[5];
    const float* bn_scale = (const float*)d_in[6];
    const float* ti_w     = (const float*)d_in[7];
    const float* ti_scale = (const float*)d_in[8];
    const float* dw_w     = (const float*)d_in[9];
    const float* pw_w     = (const float*)d_in[10];
    const float* pw_scale = (const float*)d_in[11];
    const float* tg       = (const float*)d_in[12];
    const float* tb       = (const float*)d_in[13];
    const float* tp       = (const float*)d_in[14];
    const float* fc1_w    = (const float*)d_in[15];
    const float* fc1_b    = (const float*)d_in[16];
    const float* fc1_s    = (const float*)d_in[17];
    const float* head_pr  = (const float*)d_in[18];
    const float* fco_w    = (const float*)d_in[19];
    const float* fco_b    = (const float*)d_in[20];
    const float* fco_s    = (const float*)d_in[21];
    float* out = (float*)d_out;

    char* ws = (char*)d_ws;
    size_t fmapF = (size_t)B_ * C_ * TPAD * sizeof(float);          // 109,051,904
    size_t fmapH = (size_t)B_ * C_ * TPAD * sizeof(__hip_bfloat16); // 54,525,952
    float* bufA = (float*)ws;                                        // trunk f32
    char*  SCR  = ws + fmapF;                                        // 54.5 MB scratch
    __hip_bfloat16* Xb = (__hip_bfloat16*)(ws + fmapF + fmapH);      // [t][c] bf16
    float* h0    = (float*)(ws + fmapF + 2 * fmapH);
    float* stats = h0 + B_ * C_;
    float* wsums = stats + 800;

    hipMemsetAsync(stats, 0, 1024 * sizeof(float), stream);

    // weight |.| sums
    k_absmean<<<dim3(8, 1),  256, 0, stream>>>(bn_w,  BNC * C_, 0,        wsums + 0);
    k_absmean<<<dim3(8, 1),  256, 0, stream>>>(ti_w,  C_ * BNC, 0,        wsums + 1);
    k_absmean<<<dim3(8, NT), 256, 0, stream>>>(pw_w,  C_ * C_,  C_ * C_,  wsums + 2);
    k_absmean<<<dim3(8, 1),  256, 0, stream>>>(fc1_w, H_ * C_,  0,        wsums + 26);
    k_absmean<<<dim3(1, 1),  256, 0, stream>>>(fco_w, H_,       0,        wsums + 27);

    __hip_bfloat16* SCRh = (__hip_bfloat16*)SCR;
    float invGN = 1.f / ((float)C_ * TOUT);   // E_ == C_ == 512 for both GNs

    // encoder -> SCR bf16 [e][t] (+stats slot 0); GN+PReLU+transpose -> Xb
    k_encoder<<<dim3(E_, B_), 256, 0, stream>>>(x, enc_w, SCRh, stats);
    k_gncvt<<<dim3(TPAD / 64, E_ / 64, B_), 256, 0, stream>>>(
        SCRh, Xb, stats, enc_g, enc_be, enc_pr, invGN, E_, 1);

    // bottleneck 512->256 (bf16 out [m][t] into SCR), transpose -> Xb [t][256]
    k_gemm_mfma<<<dim3(TPAD / 128, BNC / 128, B_), 256, 0, stream>>>(
        bn_w, Xb, nullptr, SCRh, wsums + 0, 1.f / (BNC * C_), bn_scale, BNC, C_, 2);
    k_gncvt<<<dim3(TPAD / 64, BNC / 64, B_), 256, 0, stream>>>(
        SCRh, Xb, nullptr, nullptr, nullptr, nullptr, 0.f, BNC, 0);

    // tcn_input 256->512 -> trunk bufA f32
    k_gemm_mfma<<<dim3(TPAD / 128, C_ / 128, B_), 256, 0, stream>>>(
        ti_w, Xb, bufA, nullptr, wsums + 1, 1.f / (C_ * BNC), ti_scale, C_, BNC, 0);

    // 24 TCN layers
    for (int i = 0; i < NT; ++i) {
        int d = 1 << (i & 7);
        float* st = stats + (1 + i) * 32;
        k_dwconv<<<dim3(C_, B_), 256, 0, stream>>>(
            bufA, dw_w + (size_t)i * C_ * 3, SCRh, st, d);
        k_gncvt<<<dim3(TPAD / 64, C_ / 64, B_), 256, 0, stream>>>(
            SCRh, Xb, st, tg + i * C_, tb + i * C_, tp + i, invGN, C_, 1);
        k_gemm_mfma<<<dim3(TPAD / 128, C_ / 128, B_), 256, 0, stream>>>(
            pw_w + (size_t)i * C_ * C_, Xb, bufA, nullptr, wsums + 2 + i,
            1.f / (C_ * C_), pw_scale + i, C_, C_, 1);
    }

    // head
    k_tmean<<<dim3(C_, B_), 256, 0, stream>>>(bufA, h0);
    k_head<<<dim3(B_), 256, 0, stream>>>(h0, fc1_w, fc1_b, fc1_s, head_pr,
                                         fco_w, fco_b, fco_s, wsums, out);
}

// Round 3
// 5830.374 us; speedup vs baseline: 2.5155x; 1.5954x over previous
//
#include <hip/hip_runtime.h>
#include <hip/hip_bf16.h>
#include <math.h>

// v3 — [t][c] bf16 layout everywhere; GN+PReLU fused into GEMM A-staging;
// encoder as MFMA GEMM (windows of x are contiguous); no transpose kernels.
//
// bit_conv1d(x,w,s) == conv(x, sign(w)) * mean|w| * s  (x_scale cancels).
//
// ws: trunk [b][t][512] bf16 | act [b][t][512] bf16 (alias: bnout [b][t][256])
//     | xe [b][t][512] bf16 | stats(800)+wsums(32)+h0(8192) f32

#define EPSF 1e-5f

constexpr int B_   = 16;
constexpr int TIN  = 64000;
constexpr int TOUT = 3201;
constexpr int TPAD = 3328;   // 26*128
constexpr int E_   = 512;
constexpr int BNC  = 256;
constexpr int C_   = 512;
constexpr int NT   = 24;
constexpr int H_   = 256;

// flags
#define FL_AX    1   // A from raw x windows (encoder)
#define FL_GN    2   // apply GN affine + PReLU during A staging
#define FL_BSIGN 4   // B = sign(W)
#define FL_RES   8   // residual add from Res
#define FL_STATS 16  // epilogue GN stats -> statsOut

typedef __attribute__((ext_vector_type(8))) short short8;
typedef __attribute__((ext_vector_type(4))) float floatx4;

__device__ __forceinline__ float b2f(short s) {
    unsigned u = ((unsigned)(unsigned short)s) << 16;
    float f; __builtin_memcpy(&f, &u, 4); return f;
}
__device__ __forceinline__ short f2b(float f) {
    __hip_bfloat16 h = __float2bfloat16(f);
    short s; __builtin_memcpy(&s, &h, 2); return s;
}
__device__ __forceinline__ short bsign(float w) {
    return (w > 0.f) ? (short)0x3F80 : ((w < 0.f) ? (short)0xBF80 : (short)0);
}
__device__ __forceinline__ float fsign(float w) {
    return (w > 0.f) ? 1.f : ((w < 0.f) ? -1.f : 0.f);
}

__device__ float blockReduceSumB(float v, float* red) {
    __syncthreads();
    int lane = threadIdx.x & 63, wid = threadIdx.x >> 6;
#pragma unroll
    for (int o = 32; o > 0; o >>= 1) v += __shfl_down(v, o, 64);
    if (lane == 0) red[wid] = v;
    __syncthreads();
    if (threadIdx.x == 0) red[0] = red[0] + red[1] + red[2] + red[3];
    __syncthreads();
    return red[0];
}

// --- sum|w| ----------------------------------------------------------------
__global__ void k_absmean(const float* __restrict__ p, int n, int slice_stride,
                          float* __restrict__ out) {
    __shared__ float red[4];
    const float* q = p + (size_t)blockIdx.y * (size_t)slice_stride;
    float s = 0.f;
    for (int i = blockIdx.x * blockDim.x + threadIdx.x; i < n;
         i += gridDim.x * blockDim.x)
        s += fabsf(q[i]);
    s = blockReduceSumB(s, red);
    if (threadIdx.x == 0) atomicAdd(out + blockIdx.y, s);
}

// --- unified MFMA GEMM:  Y[b,t,n] = alpha * sum_k A[b,t,k] * Bop[n,k] (+res)
// A: act bf16 [b][TPAD][K] (opt. GN+PReLU per-k) or x windows (FL_AX).
// Bop: f32 [N][ldb], sign() if FL_BSIGN else bf16 cast, k>=kmax -> 0.
__global__ __launch_bounds__(256) void k_gemm(
    const __hip_bfloat16* __restrict__ Aact, const float* __restrict__ xraw,
    const float* __restrict__ Bw, __hip_bfloat16* __restrict__ Yout,
    const __hip_bfloat16* __restrict__ Res,
    const float* __restrict__ gnstats, const float* __restrict__ gamma,
    const float* __restrict__ beta, const float* __restrict__ prelu, float invN,
    const float* __restrict__ wsum, float inv_nw, const float* __restrict__ scale,
    float* __restrict__ statsOut,
    int K, int N, int ldb, int kmax, int flags) {
    __shared__ __align__(16) short As[128 * 64];
    __shared__ __align__(16) short Bs[128 * 64];
    __shared__ float red[4];
    int b = blockIdx.z;
    int m0 = blockIdx.x * 128, n0 = blockIdx.y * 128;
    int tid = threadIdx.x;
    int lane = tid & 63, wid = tid >> 6;
    int wr = wid >> 1, wc = wid & 1;
    int l15 = lane & 15, quad = lane >> 4;

    float mean = 0.f, ginv = 0.f, pr = 0.f;
    if (flags & FL_GN) {
        float s0 = gnstats[b * 2], s1 = gnstats[b * 2 + 1];
        mean = s0 * invN;
        float var = s1 * invN - mean * mean;
        ginv = rsqrtf(var + EPSF);
        pr = prelu[0];
    }

    floatx4 acc[4][4];
#pragma unroll
    for (int i = 0; i < 4; ++i)
#pragma unroll
        for (int j = 0; j < 4; ++j) acc[i][j] = (floatx4){0.f, 0.f, 0.f, 0.f};

    for (int k0 = 0; k0 < K; k0 += 64) {
        // ---- A tile: 128 rows (t) x 64 k
#pragma unroll
        for (int j = 0; j < 4; ++j) {
            int id = j * 256 + tid;
            int r = id >> 3, cc = id & 7;
            int t = m0 + r;
            short8 v = (short8){0,0,0,0,0,0,0,0};
            if (flags & FL_AX) {
                if (t < TOUT && cc < 5) {           // k = cc*8..+7 < 40
                    int base = 20 * t + cc * 8 - 20;
                    const float* xp = xraw + (size_t)b * TIN;
                    if (base >= 0 && base + 8 <= TIN) {
                        float4 x0 = *(const float4*)(xp + base);
                        float4 x1 = *(const float4*)(xp + base + 4);
                        v[0]=f2b(x0.x); v[1]=f2b(x0.y); v[2]=f2b(x0.z); v[3]=f2b(x0.w);
                        v[4]=f2b(x1.x); v[5]=f2b(x1.y); v[6]=f2b(x1.z); v[7]=f2b(x1.w);
                    } else {
#pragma unroll
                        for (int e = 0; e < 8; ++e) {
                            int xi = base + e;
                            if (xi >= 0 && xi < TIN) v[e] = f2b(xp[xi]);
                        }
                    }
                }
            } else {
                const __hip_bfloat16* ap =
                    Aact + ((size_t)b * TPAD + t) * K + k0 + cc * 8;
                v = *(const short8*)ap;
                if (flags & FL_GN) {
                    int c = k0 + cc * 8;
                    float4 g0 = *(const float4*)(gamma + c);
                    float4 g1 = *(const float4*)(gamma + c + 4);
                    float4 be0 = *(const float4*)(beta + c);
                    float4 be1 = *(const float4*)(beta + c + 4);
                    float gs[8] = {g0.x,g0.y,g0.z,g0.w,g1.x,g1.y,g1.z,g1.w};
                    float bs_[8] = {be0.x,be0.y,be0.z,be0.w,be1.x,be1.y,be1.z,be1.w};
#pragma unroll
                    for (int e = 0; e < 8; ++e) {
                        float sc = gs[e] * ginv;
                        float sh = bs_[e] - mean * sc;
                        float f = b2f(v[e]) * sc + sh;
                        f = (f >= 0.f) ? f : pr * f;
                        v[e] = f2b(f);
                    }
                    if (t >= TOUT) v = (short8){0,0,0,0,0,0,0,0};
                }
            }
            *(short8*)&As[r * 64 + ((cc ^ (r & 7)) * 8)] = v;
        }
        // ---- B tile: 128 rows (n) x 64 k from f32 weights
#pragma unroll
        for (int j = 0; j < 4; ++j) {
            int id = j * 256 + tid;
            int r = id >> 3, cc = id & 7;
            const float* wp = Bw + (size_t)(n0 + r) * ldb + k0 + cc * 8;
            int kk = k0 + cc * 8;
            short8 v = (short8){0,0,0,0,0,0,0,0};
            if (kk + 8 <= kmax) {
                float4 a = *(const float4*)wp;
                float4 c4 = *(const float4*)(wp + 4);
                float wv[8] = {a.x,a.y,a.z,a.w,c4.x,c4.y,c4.z,c4.w};
                if (flags & FL_BSIGN) {
#pragma unroll
                    for (int e = 0; e < 8; ++e) v[e] = bsign(wv[e]);
                } else {
#pragma unroll
                    for (int e = 0; e < 8; ++e) v[e] = f2b(wv[e]);
                }
            } else if (kk < kmax) {
#pragma unroll
                for (int e = 0; e < 8; ++e)
                    if (kk + e < kmax)
                        v[e] = (flags & FL_BSIGN) ? bsign(wp[e]) : f2b(wp[e]);
            }
            *(short8*)&Bs[r * 64 + ((cc ^ (r & 7)) * 8)] = v;
        }
        __syncthreads();
#pragma unroll
        for (int s = 0; s < 2; ++s) {
            short8 af[4], bf[4];
#pragma unroll
            for (int i = 0; i < 4; ++i) {
                int row = wr * 64 + i * 16 + l15;
                int ch = (s * 4 + quad) ^ (row & 7);
                af[i] = *(const short8*)&As[row * 64 + ch * 8];
            }
#pragma unroll
            for (int j = 0; j < 4; ++j) {
                int row = wc * 64 + j * 16 + l15;
                int ch = (s * 4 + quad) ^ (row & 7);
                bf[j] = *(const short8*)&Bs[row * 64 + ch * 8];
            }
#pragma unroll
            for (int i = 0; i < 4; ++i)
#pragma unroll
                for (int j = 0; j < 4; ++j)
                    acc[i][j] = __builtin_amdgcn_mfma_f32_16x16x32_bf16(
                        af[i], bf[j], acc[i][j], 0, 0, 0);
        }
        __syncthreads();
    }

    float alpha = wsum ? (wsum[0] * inv_nw * scale[0]) : 1.f;
    float ls = 0.f, lq = 0.f;
#pragma unroll
    for (int i = 0; i < 4; ++i) {
#pragma unroll
        for (int j = 0; j < 4; ++j) {
            int tb = m0 + wr * 64 + i * 16 + quad * 4;
            int n  = n0 + wc * 64 + j * 16 + l15;
#pragma unroll
            for (int r = 0; r < 4; ++r) {
                int t = tb + r;
                float v = alpha * acc[i][j][r];
                size_t off = ((size_t)b * TPAD + t) * N + n;
                if (flags & FL_RES) v += b2f(*(const short*)(Res + off));
                *(short*)(Yout + off) = f2b(v);
                if ((flags & FL_STATS) && t < TOUT) { ls += v; lq += v * v; }
            }
        }
    }
    if (flags & FL_STATS) {
        ls = blockReduceSumB(ls, red);
        lq = blockReduceSumB(lq, red);
        if (tid == 0) {
            atomicAdd(statsOut + b * 2, ls);
            atomicAdd(statsOut + b * 2 + 1, lq);
        }
    }
}

// --- depthwise conv k=3 dil d, [t][c] bf16 -> [t][c] bf16 + GN stats -------
__global__ __launch_bounds__(256) void k_dwconv(
    const __hip_bfloat16* __restrict__ trunk, const float* __restrict__ w,
    __hip_bfloat16* __restrict__ act, float* __restrict__ stats, int d) {
    __shared__ float red[4];
    int b = blockIdx.y, t0 = blockIdx.x * 128;
    int tid = threadIdx.x, lane = tid & 63, wv = tid >> 6;
    int c8 = lane * 8;
    float wr[24];
    const float4* wp4 = (const float4*)(w + c8 * 3);
#pragma unroll
    for (int q = 0; q < 6; ++q) ((float4*)wr)[q] = wp4[q];
    const __hip_bfloat16* base = trunk + (size_t)b * TPAD * C_;
    __hip_bfloat16* ob = act + (size_t)b * TPAD * C_;
    float ls = 0.f, lq = 0.f;
    for (int it = 0; it < 32; ++it) {
        int t = t0 + it * 4 + wv;
        if (t < TOUT) {
            short8 mid = *(const short8*)(base + (size_t)t * C_ + c8);
            short8 prv = (t >= d) ? *(const short8*)(base + (size_t)(t - d) * C_ + c8)
                                  : (short8){0,0,0,0,0,0,0,0};
            short8 nxt = (t + d < TPAD) ? *(const short8*)(base + (size_t)(t + d) * C_ + c8)
                                        : (short8){0,0,0,0,0,0,0,0};
            short8 o;
#pragma unroll
            for (int e = 0; e < 8; ++e) {
                float v = wr[e * 3 + 1] * b2f(mid[e])
                        + wr[e * 3 + 0] * b2f(prv[e])
                        + wr[e * 3 + 2] * b2f(nxt[e]);
                o[e] = f2b(v); ls += v; lq += v * v;
            }
            *(short8*)(ob + (size_t)t * C_ + c8) = o;
        } else {
            *(short8*)(ob + (size_t)t * C_ + c8) = (short8){0,0,0,0,0,0,0,0};
        }
    }
    ls = blockReduceSumB(ls, red);
    lq = blockReduceSumB(lq, red);
    if (tid == 0) {
        atomicAdd(stats + b * 2, ls);
        atomicAdd(stats + b * 2 + 1, lq);
    }
}

// --- temporal sum (atomic into h0; divide in head) -------------------------
__global__ void k_tmean(const __hip_bfloat16* __restrict__ trunk,
                        float* __restrict__ h0) {
    int b = blockIdx.y, t0 = blockIdx.x * 128;
    int tid = threadIdx.x;
    const __hip_bfloat16* base = trunk + (size_t)b * TPAD * C_;
    float s0 = 0.f, s1 = 0.f;
    for (int it = 0; it < 128; ++it) {
        int t = t0 + it;
        if (t >= TOUT) break;
        s0 += b2f(*(const short*)(base + (size_t)t * C_ + tid));
        s1 += b2f(*(const short*)(base + (size_t)t * C_ + tid + 256));
    }
    atomicAdd(h0 + b * C_ + tid, s0);
    atomicAdd(h0 + b * C_ + tid + 256, s1);
}

// --- head ------------------------------------------------------------------
__global__ void k_head(const float* __restrict__ h0,
                       const float* __restrict__ fc1_w, const float* __restrict__ fc1_b,
                       const float* __restrict__ fc1_scale, const float* __restrict__ head_prelu,
                       const float* __restrict__ fco_w, const float* __restrict__ fco_b,
                       const float* __restrict__ fco_scale,
                       const float* __restrict__ wsums, float* __restrict__ out) {
    __shared__ float sh0[512];
    __shared__ float red[4];
    int b = blockIdx.x, tid = threadIdx.x;
    sh0[tid]       = h0[b * C_ + tid] / (float)TOUT;
    sh0[tid + 256] = h0[b * C_ + 256 + tid] / (float)TOUT;
    __syncthreads();
    float av = fabsf(sh0[tid]) + fabsf(sh0[tid + 256]);
    float xs1 = blockReduceSumB(av, red) / 512.f;
    xs1 = fmaxf(xs1, EPSF);
    float ws1 = wsums[26] / 131072.f;
    float sc1 = fc1_scale[0];
    const float* wrow = fc1_w + tid * 512;
    float s = 0.f;
    for (int c = 0; c < 512; ++c) s += sh0[c] * fsign(wrow[c]);
    float h1 = s * ws1 * sc1 + fc1_b[tid] * ws1 * xs1 * sc1;
    float a = head_prelu[0];
    h1 = (h1 >= 0.f) ? h1 : a * h1;
    float xs2 = blockReduceSumB(fabsf(h1), red) / 256.f;
    xs2 = fmaxf(xs2, EPSF);
    float zpart = h1 * fsign(fco_w[tid]);
    float z = blockReduceSumB(zpart, red);
    if (tid == 0) {
        float ws2 = wsums[27] / 256.f;
        float sc2 = fco_scale[0];
        z = z * ws2 * sc2 + fco_b[0] * ws2 * xs2 * sc2;
        out[b] = 1.f / (1.f + expf(-z));
    }
}

extern "C" void kernel_launch(void* const* d_in, const int* in_sizes, int n_in,
                              void* d_out, int out_size, void* d_ws, size_t ws_size,
                              hipStream_t stream) {
    const float* x        = (const float*)d_in[0];
    const float* enc_w    = (const float*)d_in[1];
    const float* enc_g    = (const float*)d_in[2];
    const float* enc_be   = (const float*)d_in[3];
    const float* enc_pr   = (const float*)d_in[4];
    const float* bn_w     = (const float*)d_in[5];
    const float* bn_scale = (const float*)d_in[6];
    const float* ti_w     = (const float*)d_in[7];
    const float* ti_scale = (const float*)d_in[8];
    const float* dw_w     = (const float*)d_in[9];
    const float* pw_w     = (const float*)d_in[10];
    const float* pw_scale = (const float*)d_in[11];
    const float* tg       = (const float*)d_in[12];
    const float* tb       = (const float*)d_in[13];
    const float* tp       = (const float*)d_in[14];
    const float* fc1_w    = (const float*)d_in[15];
    const float* fc1_b    = (const float*)d_in[16];
    const float* fc1_s    = (const float*)d_in[17];
    const float* head_pr  = (const float*)d_in[18];
    const float* fco_w    = (const float*)d_in[19];
    const float* fco_b    = (const float*)d_in[20];
    const float* fco_s    = (const float*)d_in[21];
    float* out = (float*)d_out;

    char* ws = (char*)d_ws;
    size_t fmapH = (size_t)B_ * TPAD * C_ * sizeof(__hip_bfloat16); // 54,525,952
    __hip_bfloat16* trunk = (__hip_bfloat16*)ws;
    __hip_bfloat16* act   = (__hip_bfloat16*)(ws + fmapH);   // also bnout
    __hip_bfloat16* xe    = (__hip_bfloat16*)(ws + 2 * fmapH);
    float* stats = (float*)(ws + 3 * fmapH);
    float* wsums = stats + 800;
    float* h0    = stats + 832;

    hipMemsetAsync(stats, 0, (832 + B_ * C_) * sizeof(float), stream);

    k_absmean<<<dim3(8, 1),  256, 0, stream>>>(bn_w,  BNC * C_, 0,        wsums + 0);
    k_absmean<<<dim3(8, 1),  256, 0, stream>>>(ti_w,  C_ * BNC, 0,        wsums + 1);
    k_absmean<<<dim3(8, NT), 256, 0, stream>>>(pw_w,  C_ * C_,  C_ * C_,  wsums + 2);
    k_absmean<<<dim3(8, 1),  256, 0, stream>>>(fc1_w, H_ * C_,  0,        wsums + 26);
    k_absmean<<<dim3(1, 1),  256, 0, stream>>>(fco_w, H_,       0,        wsums + 27);

    float invGN = 1.f / ((float)C_ * TOUT);   // E_ == C_ == 512

    // encoder: x windows (K=40 pad 64) x enc_w -> xe [t][512] bf16 + stats0
    k_gemm<<<dim3(TPAD / 128, E_ / 128, B_), 256, 0, stream>>>(
        nullptr, x, enc_w, xe, nullptr,
        nullptr, nullptr, nullptr, nullptr, 0.f,
        nullptr, 0.f, nullptr, stats,
        64, E_, 40, 40, FL_AX | FL_STATS);

    // bottleneck: GN(enc)+PReLU fused; sign(bn_w); -> bnout(act) [t][256]
    k_gemm<<<dim3(TPAD / 128, BNC / 128, B_), 256, 0, stream>>>(
        xe, nullptr, bn_w, act, nullptr,
        stats, enc_g, enc_be, enc_pr, invGN,
        wsums + 0, 1.f / (BNC * C_), bn_scale, nullptr,
        E_, BNC, E_, E_, FL_GN | FL_BSIGN);

    // tcn_input: raw bnout; sign(ti_w); -> trunk [t][512]
    k_gemm<<<dim3(TPAD / 128, C_ / 128, B_), 256, 0, stream>>>(
        act, nullptr, ti_w, trunk, nullptr,
        nullptr, nullptr, nullptr, nullptr, 0.f,
        wsums + 1, 1.f / (C_ * BNC), ti_scale, nullptr,
        BNC, C_, BNC, BNC, FL_BSIGN);

    for (int i = 0; i < NT; ++i) {
        int d = 1 << (i & 7);
        float* st = stats + (1 + i) * 32;
        k_dwconv<<<dim3(TPAD / 128, B_), 256, 0, stream>>>(
            trunk, dw_w + (size_t)i * C_ * 3, act, st, d);
        k_gemm<<<dim3(TPAD / 128, C_ / 128, B_), 256, 0, stream>>>(
            act, nullptr, pw_w + (size_t)i * C_ * C_, trunk, trunk,
            st, tg + i * C_, tb + i * C_, tp + i, invGN,
            wsums + 2 + i, 1.f / (C_ * C_), pw_scale + i, nullptr,
            C_, C_, C_, C_, FL_GN | FL_BSIGN | FL_RES);
    }

    k_tmean<<<dim3(TPAD / 128, B_), 256, 0, stream>>>(trunk, h0);
    k_head<<<dim3(B_), 256, 0, stream>>>(h0, fc1_w, fc1_b, fc1_s, head_pr,
                                         fco_w, fco_b, fco_s, wsums, out);
}

// Round 4
// 3771.388 us; speedup vs baseline: 3.8889x; 1.5459x over previous
//
#include <hip/hip_runtime.h>
#include <hip/hip_bf16.h>
#include <math.h>

// v4 — pre-converted bf16 sign weights, software-pipelined K-loop (register
// prefetch over single LDS buffer), GN scale/shift in LDS, XCD-aware swizzle.
//
// bit_conv1d(x,w,s) == conv(x, sign(w)) * mean|w| * s  (x_scale cancels).

#define EPSF 1e-5f

constexpr int B_   = 16;
constexpr int TIN  = 64000;
constexpr int TOUT = 3201;
constexpr int TPAD = 3328;   // 26*128
constexpr int E_   = 512;
constexpr int BNC  = 256;
constexpr int C_   = 512;
constexpr int NT   = 24;
constexpr int H_   = 256;
constexpr int NM   = TPAD / 128;  // 26

#define FL_AX    1   // A from raw x windows (encoder)
#define FL_GN    2   // apply GN affine + PReLU during A staging (K must be 512)
#define FL_RES   8   // residual add from Res
#define FL_STATS 16  // epilogue GN stats -> statsOut

typedef __attribute__((ext_vector_type(8))) short short8;
typedef __attribute__((ext_vector_type(4))) float floatx4;

__device__ __forceinline__ float b2f(short s) {
    unsigned u = ((unsigned)(unsigned short)s) << 16;
    float f; __builtin_memcpy(&f, &u, 4); return f;
}
__device__ __forceinline__ short f2b(float f) {
    __hip_bfloat16 h = __float2bfloat16(f);
    short s; __builtin_memcpy(&s, &h, 2); return s;
}
__device__ __forceinline__ short bsign(float w) {
    return (w > 0.f) ? (short)0x3F80 : ((w < 0.f) ? (short)0xBF80 : (short)0);
}
__device__ __forceinline__ float fsign(float w) {
    return (w > 0.f) ? 1.f : ((w < 0.f) ? -1.f : 0.f);
}

__device__ float blockReduceSumB(float v, float* red) {
    __syncthreads();
    int lane = threadIdx.x & 63, wid = threadIdx.x >> 6;
#pragma unroll
    for (int o = 32; o > 0; o >>= 1) v += __shfl_down(v, o, 64);
    if (lane == 0) red[wid] = v;
    __syncthreads();
    if (threadIdx.x == 0) red[0] = red[0] + red[1] + red[2] + red[3];
    __syncthreads();
    return red[0];
}

// --- weight prep -----------------------------------------------------------
__global__ void k_signcvt(const float* __restrict__ src,
                          __hip_bfloat16* __restrict__ dst, int n) {
    int i = (blockIdx.x * 256 + threadIdx.x) * 8;
    if (i >= n) return;
    float4 a = *(const float4*)(src + i);
    float4 c = *(const float4*)(src + i + 4);
    short8 v;
    v[0]=bsign(a.x); v[1]=bsign(a.y); v[2]=bsign(a.z); v[3]=bsign(a.w);
    v[4]=bsign(c.x); v[5]=bsign(c.y); v[6]=bsign(c.z); v[7]=bsign(c.w);
    *(short8*)(dst + i) = v;
}

__global__ void k_encw(const float* __restrict__ src,
                       __hip_bfloat16* __restrict__ dst) {
    int id = blockIdx.x * 256 + threadIdx.x;   // 4096 threads
    int r = id >> 3, cc = id & 7;
    short8 v = (short8){0,0,0,0,0,0,0,0};
    if (cc < 5) {
        const float* s = src + r * 40 + cc * 8;
#pragma unroll
        for (int e = 0; e < 8; ++e) v[e] = f2b(s[e]);
    }
    *(short8*)(dst + r * 64 + cc * 8) = v;
}

// --- sum|w| ----------------------------------------------------------------
__global__ void k_absmean(const float* __restrict__ p, int n, int slice_stride,
                          float* __restrict__ out) {
    __shared__ float red[4];
    const float* q = p + (size_t)blockIdx.y * (size_t)slice_stride;
    float s = 0.f;
    for (int i = blockIdx.x * blockDim.x + threadIdx.x; i < n;
         i += gridDim.x * blockDim.x)
        s += fabsf(q[i]);
    s = blockReduceSumB(s, red);
    if (threadIdx.x == 0) atomicAdd(out + blockIdx.y, s);
}

// --- pipelined MFMA GEMM:  Y[b,t,n] = alpha * sum_k A'[b,t,k] * Bw[n,k] ----
// A: act bf16 [b][TPAD][K] (opt. GN+PReLU per-k) or raw-x windows (FL_AX).
// Bw: bf16 [N][K] pre-converted (sign or padded encoder weights).
__global__ __launch_bounds__(256) void k_gemm(
    const __hip_bfloat16* __restrict__ Aact, const float* __restrict__ xraw,
    const __hip_bfloat16* __restrict__ Bw, __hip_bfloat16* __restrict__ Yout,
    const __hip_bfloat16* __restrict__ Res,
    const float* __restrict__ gnstats, const float* __restrict__ gamma,
    const float* __restrict__ beta, const float* __restrict__ prelu, float invN,
    const float* __restrict__ wsum, float inv_nw, const float* __restrict__ scale,
    float* __restrict__ statsOut,
    int K, int N, int nnshift, int flags) {
    __shared__ __align__(16) short As[128 * 64];
    __shared__ __align__(16) short Bs[128 * 64];
    __shared__ float2 scsh[576];   // GN scale/shift, bank-conflict padded
    __shared__ float red[4];

    int tid = threadIdx.x;
    // XCD-aware swizzle: n-blocks sharing an A-tile get same (gid & 7) -> same XCD
    int gid = blockIdx.x;
    int xcd = gid & 7, grp = gid >> 3;
    int nidx = grp & ((1 << nnshift) - 1);
    int mb = (grp >> nnshift) * 8 + xcd;
    int m0 = (mb % NM) * 128;
    int b  = mb / NM;
    int n0 = nidx * 128;

    int lane = tid & 63, wid = tid >> 6;
    int wr = wid >> 1, wc = wid & 1;
    int l15 = lane & 15, quad = lane >> 4;

    float pr = 0.f;
    if (flags & FL_GN) {
        float s0 = gnstats[b * 2], s1 = gnstats[b * 2 + 1];
        float mean = s0 * invN;
        float var  = s1 * invN - mean * mean;
        float ginv = rsqrtf(var + EPSF);
        pr = prelu[0];
        int k = tid * 2;
        float sc0 = gamma[k] * ginv, sc1 = gamma[k + 1] * ginv;
        scsh[k + (k >> 3)] = make_float2(sc0, beta[k] - mean * sc0);
        int k2 = k + 1;
        scsh[k2 + (k2 >> 3)] = make_float2(sc1, beta[k + 1] - mean * sc1);
    }

    floatx4 acc[4][4];
#pragma unroll
    for (int i = 0; i < 4; ++i)
#pragma unroll
        for (int j = 0; j < 4; ++j) acc[i][j] = (floatx4){0.f, 0.f, 0.f, 0.f};

    short8 ra[4], rb[4];
    int nk = K >> 6;

    auto loadTile = [&](int kt) {
        int k0 = kt * 64;
        if (flags & FL_AX) {
            const float* xp = xraw + (size_t)b * TIN;
#pragma unroll
            for (int j = 0; j < 4; ++j) {
                int id = j * 256 + tid;
                int r = id >> 3, cc = id & 7;
                int t = m0 + r;
                short8 v = (short8){0,0,0,0,0,0,0,0};
                if (t < TOUT && cc < 5) {
                    int base = 20 * t + cc * 8 - 20;
                    if (base >= 0 && base + 8 <= TIN) {
                        float4 x0 = *(const float4*)(xp + base);
                        float4 x1 = *(const float4*)(xp + base + 4);
                        v[0]=f2b(x0.x); v[1]=f2b(x0.y); v[2]=f2b(x0.z); v[3]=f2b(x0.w);
                        v[4]=f2b(x1.x); v[5]=f2b(x1.y); v[6]=f2b(x1.z); v[7]=f2b(x1.w);
                    } else {
#pragma unroll
                        for (int e = 0; e < 8; ++e) {
                            int xi = base + e;
                            if (xi >= 0 && xi < TIN) v[e] = f2b(xp[xi]);
                        }
                    }
                }
                ra[j] = v;
            }
        } else {
#pragma unroll
            for (int j = 0; j < 4; ++j) {
                int id = j * 256 + tid;
                int r = id >> 3, cc = id & 7;
                ra[j] = *(const short8*)(Aact + ((size_t)b * TPAD + m0 + r) * K
                                         + k0 + cc * 8);
            }
        }
#pragma unroll
        for (int j = 0; j < 4; ++j) {
            int id = j * 256 + tid;
            int r = id >> 3, cc = id & 7;
            rb[j] = *(const short8*)(Bw + (size_t)(n0 + r) * K + k0 + cc * 8);
        }
    };

    loadTile(0);
    for (int kt = 0; kt < nk; ++kt) {
        __syncthreads();   // prior MFMA done with LDS; also covers scsh init
        int k0 = kt * 64;
#pragma unroll
        for (int j = 0; j < 4; ++j) {
            int id = j * 256 + tid;
            int r = id >> 3, cc = id & 7;
            short8 v = ra[j];
            if (flags & FL_GN) {
                if (m0 + r < TOUT) {
                    int kk = k0 + cc * 8;
                    const float2* ss = &scsh[kk + (kk >> 3)];
#pragma unroll
                    for (int e = 0; e < 8; ++e) {
                        float2 s2 = ss[e];
                        float f = b2f(v[e]) * s2.x + s2.y;
                        f = (f >= 0.f) ? f : pr * f;
                        v[e] = f2b(f);
                    }
                } else {
                    v = (short8){0,0,0,0,0,0,0,0};
                }
            }
            int sw = (cc ^ (r & 7)) * 8;
            *(short8*)&As[r * 64 + sw] = v;
            *(short8*)&Bs[r * 64 + sw] = rb[j];
        }
        __syncthreads();
        if (kt + 1 < nk) loadTile(kt + 1);   // in flight during MFMA
#pragma unroll
        for (int s = 0; s < 2; ++s) {
            short8 af[4], bf[4];
#pragma unroll
            for (int i = 0; i < 4; ++i) {
                int row = wr * 64 + i * 16 + l15;
                int ch = (s * 4 + quad) ^ (row & 7);
                af[i] = *(const short8*)&As[row * 64 + ch * 8];
            }
#pragma unroll
            for (int j = 0; j < 4; ++j) {
                int row = wc * 64 + j * 16 + l15;
                int ch = (s * 4 + quad) ^ (row & 7);
                bf[j] = *(const short8*)&Bs[row * 64 + ch * 8];
            }
#pragma unroll
            for (int i = 0; i < 4; ++i)
#pragma unroll
                for (int j = 0; j < 4; ++j)
                    acc[i][j] = __builtin_amdgcn_mfma_f32_16x16x32_bf16(
                        af[i], bf[j], acc[i][j], 0, 0, 0);
        }
    }

    float alpha = wsum ? (wsum[0] * inv_nw * scale[0]) : 1.f;
    float ls = 0.f, lq = 0.f;
#pragma unroll
    for (int i = 0; i < 4; ++i) {
#pragma unroll
        for (int j = 0; j < 4; ++j) {
            int tb = m0 + wr * 64 + i * 16 + quad * 4;
            int n  = n0 + wc * 64 + j * 16 + l15;
#pragma unroll
            for (int r = 0; r < 4; ++r) {
                int t = tb + r;
                float v = alpha * acc[i][j][r];
                size_t off = ((size_t)b * TPAD + t) * N + n;
                if (flags & FL_RES) v += b2f(*(const short*)(Res + off));
                *(short*)(Yout + off) = f2b(v);
                if ((flags & FL_STATS) && t < TOUT) { ls += v; lq += v * v; }
            }
        }
    }
    if (flags & FL_STATS) {
        ls = blockReduceSumB(ls, red);
        lq = blockReduceSumB(lq, red);
        if (tid == 0) {
            atomicAdd(statsOut + b * 2, ls);
            atomicAdd(statsOut + b * 2 + 1, lq);
        }
    }
}

// --- depthwise conv k=3 dil d, [t][c] bf16 -> [t][c] bf16 + GN stats -------
__global__ __launch_bounds__(256) void k_dwconv(
    const __hip_bfloat16* __restrict__ trunk, const float* __restrict__ w,
    __hip_bfloat16* __restrict__ act, float* __restrict__ stats, int d) {
    __shared__ float red[4];
    int b = blockIdx.y, t0 = blockIdx.x * 128;
    int tid = threadIdx.x, lane = tid & 63, wv = tid >> 6;
    int c8 = lane * 8;
    float wr[24];
    const float4* wp4 = (const float4*)(w + c8 * 3);
#pragma unroll
    for (int q = 0; q < 6; ++q) ((float4*)wr)[q] = wp4[q];
    const __hip_bfloat16* base = trunk + (size_t)b * TPAD * C_;
    __hip_bfloat16* ob = act + (size_t)b * TPAD * C_;
    float ls = 0.f, lq = 0.f;
    for (int it = 0; it < 32; ++it) {
        int t = t0 + it * 4 + wv;
        if (t < TOUT) {
            short8 mid = *(const short8*)(base + (size_t)t * C_ + c8);
            short8 prv = (t >= d) ? *(const short8*)(base + (size_t)(t - d) * C_ + c8)
                                  : (short8){0,0,0,0,0,0,0,0};
            short8 nxt = (t + d < TPAD) ? *(const short8*)(base + (size_t)(t + d) * C_ + c8)
                                        : (short8){0,0,0,0,0,0,0,0};
            short8 o;
#pragma unroll
            for (int e = 0; e < 8; ++e) {
                float v = wr[e * 3 + 1] * b2f(mid[e])
                        + wr[e * 3 + 0] * b2f(prv[e])
                        + wr[e * 3 + 2] * b2f(nxt[e]);
                o[e] = f2b(v); ls += v; lq += v * v;
            }
            *(short8*)(ob + (size_t)t * C_ + c8) = o;
        } else {
            *(short8*)(ob + (size_t)t * C_ + c8) = (short8){0,0,0,0,0,0,0,0};
        }
    }
    ls = blockReduceSumB(ls, red);
    lq = blockReduceSumB(lq, red);
    if (tid == 0) {
        atomicAdd(stats + b * 2, ls);
        atomicAdd(stats + b * 2 + 1, lq);
    }
}

// --- temporal sum ----------------------------------------------------------
__global__ void k_tmean(const __hip_bfloat16* __restrict__ trunk,
                        float* __restrict__ h0) {
    int b = blockIdx.y, t0 = blockIdx.x * 128;
    int tid = threadIdx.x;
    const __hip_bfloat16* base = trunk + (size_t)b * TPAD * C_;
    float s0 = 0.f, s1 = 0.f;
    for (int it = 0; it < 128; ++it) {
        int t = t0 + it;
        if (t >= TOUT) break;
        s0 += b2f(*(const short*)(base + (size_t)t * C_ + tid));
        s1 += b2f(*(const short*)(base + (size_t)t * C_ + tid + 256));
    }
    atomicAdd(h0 + b * C_ + tid, s0);
    atomicAdd(h0 + b * C_ + tid + 256, s1);
}

// --- head ------------------------------------------------------------------
__global__ void k_head(const float* __restrict__ h0,
                       const float* __restrict__ fc1_w, const float* __restrict__ fc1_b,
                       const float* __restrict__ fc1_scale, const float* __restrict__ head_prelu,
                       const float* __restrict__ fco_w, const float* __restrict__ fco_b,
                       const float* __restrict__ fco_scale,
                       const float* __restrict__ wsums, float* __restrict__ out) {
    __shared__ float sh0[512];
    __shared__ float red[4];
    int b = blockIdx.x, tid = threadIdx.x;
    sh0[tid]       = h0[b * C_ + tid] / (float)TOUT;
    sh0[tid + 256] = h0[b * C_ + 256 + tid] / (float)TOUT;
    __syncthreads();
    float av = fabsf(sh0[tid]) + fabsf(sh0[tid + 256]);
    float xs1 = blockReduceSumB(av, red) / 512.f;
    xs1 = fmaxf(xs1, EPSF);
    float ws1 = wsums[26] / 131072.f;
    float sc1 = fc1_scale[0];
    const float* wrow = fc1_w + tid * 512;
    float s = 0.f;
    for (int c = 0; c < 512; ++c) s += sh0[c] * fsign(wrow[c]);
    float h1 = s * ws1 * sc1 + fc1_b[tid] * ws1 * xs1 * sc1;
    float a = head_prelu[0];
    h1 = (h1 >= 0.f) ? h1 : a * h1;
    float xs2 = blockReduceSumB(fabsf(h1), red) / 256.f;
    xs2 = fmaxf(xs2, EPSF);
    float zpart = h1 * fsign(fco_w[tid]);
    float z = blockReduceSumB(zpart, red);
    if (tid == 0) {
        float ws2 = wsums[27] / 256.f;
        float sc2 = fco_scale[0];
        z = z * ws2 * sc2 + fco_b[0] * ws2 * xs2 * sc2;
        out[b] = 1.f / (1.f + expf(-z));
    }
}

extern "C" void kernel_launch(void* const* d_in, const int* in_sizes, int n_in,
                              void* d_out, int out_size, void* d_ws, size_t ws_size,
                              hipStream_t stream) {
    const float* x        = (const float*)d_in[0];
    const float* enc_w    = (const float*)d_in[1];
    const float* enc_g    = (const float*)d_in[2];
    const float* enc_be   = (const float*)d_in[3];
    const float* enc_pr   = (const float*)d_in[4];
    const float* bn_w     = (const float*)d_in[5];
    const float* bn_scale = (const float*)d_in[6];
    const float* ti_w     = (const float*)d_in[7];
    const float* ti_scale = (const float*)d_in[8];
    const float* dw_w     = (const float*)d_in[9];
    const float* pw_w     = (const float*)d_in[10];
    const float* pw_scale = (const float*)d_in[11];
    const float* tg       = (const float*)d_in[12];
    const float* tb       = (const float*)d_in[13];
    const float* tp       = (const float*)d_in[14];
    const float* fc1_w    = (const float*)d_in[15];
    const float* fc1_b    = (const float*)d_in[16];
    const float* fc1_s    = (const float*)d_in[17];
    const float* head_pr  = (const float*)d_in[18];
    const float* fco_w    = (const float*)d_in[19];
    const float* fco_b    = (const float*)d_in[20];
    const float* fco_s    = (const float*)d_in[21];
    float* out = (float*)d_out;

    char* ws = (char*)d_ws;
    size_t fmapH = (size_t)B_ * TPAD * C_ * sizeof(__hip_bfloat16); // 54,525,952
    __hip_bfloat16* trunk = (__hip_bfloat16*)ws;
    __hip_bfloat16* act   = (__hip_bfloat16*)(ws + fmapH);
    __hip_bfloat16* xe    = (__hip_bfloat16*)(ws + 2 * fmapH);
    __hip_bfloat16* wenc  = (__hip_bfloat16*)(ws + 3 * fmapH);
    __hip_bfloat16* wbn   = wenc + 512 * 64;
    __hip_bfloat16* wti   = wbn + 256 * 512;
    __hip_bfloat16* wpw   = wti + 512 * 256;
    float* stats = (float*)(wpw + (size_t)NT * 512 * 512);
    float* wsums = stats + 800;
    float* h0    = stats + 832;

    hipMemsetAsync(stats, 0, (832 + B_ * C_) * sizeof(float), stream);

    // weight prep
    k_encw<<<16, 256, 0, stream>>>(enc_w, wenc);
    k_signcvt<<<(256 * 512) / 2048, 256, 0, stream>>>(bn_w, wbn, 256 * 512);
    k_signcvt<<<(512 * 256) / 2048, 256, 0, stream>>>(ti_w, wti, 512 * 256);
    k_signcvt<<<(NT * 512 * 512) / 2048, 256, 0, stream>>>(pw_w, wpw, NT * 512 * 512);

    k_absmean<<<dim3(8, 1),  256, 0, stream>>>(bn_w,  BNC * C_, 0,        wsums + 0);
    k_absmean<<<dim3(8, 1),  256, 0, stream>>>(ti_w,  C_ * BNC, 0,        wsums + 1);
    k_absmean<<<dim3(8, NT), 256, 0, stream>>>(pw_w,  C_ * C_,  C_ * C_,  wsums + 2);
    k_absmean<<<dim3(8, 1),  256, 0, stream>>>(fc1_w, H_ * C_,  0,        wsums + 26);
    k_absmean<<<dim3(1, 1),  256, 0, stream>>>(fco_w, H_,       0,        wsums + 27);

    float invGN = 1.f / ((float)C_ * TOUT);   // E_ == C_ == 512

    // encoder: x windows (K=40 pad 64) x enc_w -> xe [t][512] + stats slot 0
    k_gemm<<<NM * 4 * B_, 256, 0, stream>>>(
        nullptr, x, wenc, xe, nullptr,
        nullptr, nullptr, nullptr, nullptr, 0.f,
        nullptr, 0.f, nullptr, stats,
        64, E_, 2, FL_AX | FL_STATS);

    // bottleneck: GN(enc)+PReLU fused; -> act [t][256]
    k_gemm<<<NM * 2 * B_, 256, 0, stream>>>(
        xe, nullptr, wbn, act, nullptr,
        stats, enc_g, enc_be, enc_pr, invGN,
        wsums + 0, 1.f / (BNC * C_), bn_scale, nullptr,
        E_, BNC, 1, FL_GN);

    // tcn_input: -> trunk [t][512]
    k_gemm<<<NM * 4 * B_, 256, 0, stream>>>(
        act, nullptr, wti, trunk, nullptr,
        nullptr, nullptr, nullptr, nullptr, 0.f,
        wsums + 1, 1.f / (C_ * BNC), ti_scale, nullptr,
        BNC, C_, 2, 0);

    for (int i = 0; i < NT; ++i) {
        int d = 1 << (i & 7);
        float* st = stats + (1 + i) * 32;
        k_dwconv<<<dim3(NM, B_), 256, 0, stream>>>(
            trunk, dw_w + (size_t)i * C_ * 3, act, st, d);
        k_gemm<<<NM * 4 * B_, 256, 0, stream>>>(
            act, nullptr, wpw + (size_t)i * C_ * C_, trunk, trunk,
            st, tg + i * C_, tb + i * C_, tp + i, invGN,
            wsums + 2 + i, 1.f / (C_ * C_), pw_scale + i, nullptr,
            C_, C_, 2, FL_GN | FL_RES);
    }

    k_tmean<<<dim3(NM, B_), 256, 0, stream>>>(trunk, h0);
    k_head<<<B_, 256, 0, stream>>>(h0, fc1_w, fc1_b, fc1_s, head_pr,
                                   fco_w, fco_b, fco_s, wsums, out);
}